// Round 3
// baseline (164.902 us; speedup 1.0000x reference)
//
#include <hip/hip_runtime.h>

// Fused CRF NLL: B=1024, T=2048, K=9 (START=7, STOP=8).
// TWO-KERNEL structure to fix per-CU load imbalance (R2: duration was the
// makespan of the worst CU, which held only 4 random sentences).
//
// Kernel A (crf_chunk_kernel), B*2 blocks x 256 thr:
//   wave = one SLICE s (8 chunks) of sentence b, strided map W = bid*4+widx,
//   s = W/B, b = W%B  -> each CU averages 32 iid slices (spread +-15% vs 45%).
//   Per wave: 8 chunk 7x7 linear-space transfer matrices (dynamic
//   Lb = ceil((len-1)/64), <=32 serial steps; E in SGPRs; lane l loads only
//   f[t][l], shares exp via ds_bpermute; 4-step groups, renorm/4) then an
//   in-wave 8->1 log-matmul fold (7 steps, lane(j,i) layout), segment matrix
//   written to workspace seg[b][s][64].
// Kernel B (crf_fold_kernel), B blocks x 256 thr:
//   gold score (unrolled-8, proven) + stage 8 segment mats to LDS +
//   replicated-alpha fold over 8 segments + STOP readout,
//   atomicAdd((fwd-gold)/B).

#define START_TAG 7
#define STOP_TAG  8
#define KDIM      9
#define NS        7
#define CPS       64          // chunks per sentence
#define SLICES    8           // waves (slices) per sentence
#define NEGINF    (-1e30f)

__device__ __forceinline__ float rfl(float x) {
    return __int_as_float(__builtin_amdgcn_readfirstlane(__float_as_int(x)));
}

// ---------------------------------------------------------------- kernel A --
__global__ __launch_bounds__(256, 8) void crf_chunk_kernel(
    const float* __restrict__ feats,
    const float* __restrict__ trans,
    const int*   __restrict__ lengths,
    float* __restrict__ g_seg,
    int B, int T)
{
    __shared__ float s_E[49];
    __shared__ float s_M[4 * 512];       // per-wave 8 chunk mats [k][j*8+i]

    const int tid = threadIdx.x;
    if (tid < 49) s_E[tid] = __expf(trans[(tid / 7) * 9 + (tid % 7)]);
    __syncthreads();

    const int widx = tid >> 6;
    const int W    = blockIdx.x * 4 + widx;     // global wave id in [0, 8B)
    const int s    = W / B;                     // slice 0..7
    const int b    = W - s * B;                 // sentence

    const int    len   = lengths[b];
    const float* fbase = feats + (size_t)b * T * KDIM;
    const int    Lb    = (len > 1) ? ((len - 1 + CPS - 1) / CPS) : 1;

    // ---- phase 2: 8 chunk matrices for this slice ----
    {
        const int lane8  = tid & 7;
        const int k      = (tid >> 3) & 7;      // chunk-in-slice
        const int c      = s * 8 + k;           // global chunk of sentence
        const int tstart = 1 + c * Lb;
        const int tend   = min(tstart + Lb, len);

        if (lane8 < NS) {
            float* Mw = s_M + widx * 512 + k * 64;
            if (tstart < tend) {
                float E[49];
                #pragma unroll
                for (int e = 0; e < 49; ++e) E[e] = rfl(s_E[e]);

                int baddr[NS];
                #pragma unroll
                for (int j = 0; j < NS; ++j) baddr[j] = (((tid & 56) | j) << 2);

                float p[NS];
                #pragma unroll
                for (int j = 0; j < NS; ++j) p[j] = (j == lane8) ? 1.f : 0.f;
                float sc = 0.f;
                int rem = tend - tstart;

                const float* fp = fbase + (size_t)tstart * KDIM + lane8;

                #define CRF_MAT(EF) do {                                        \
                    float q[NS];                                                \
                    _Pragma("unroll")                                           \
                    for (int j = 0; j < NS; ++j) {                              \
                        float acc = E[j * 7] * p[0];                            \
                        _Pragma("unroll")                                       \
                        for (int i = 1; i < NS; ++i)                            \
                            acc = fmaf(E[j * 7 + i], p[i], acc);                \
                        q[j] = acc;                                             \
                    }                                                           \
                    _Pragma("unroll")                                           \
                    for (int j = 0; j < NS; ++j) p[j] = q[j] * EF[j];           \
                } while (0)

                #define CRF_BCAST(DST, XF) do {                                 \
                    float _e = __expf(XF);                                      \
                    _Pragma("unroll")                                           \
                    for (int j = 0; j < NS; ++j)                                \
                        DST[j] = __int_as_float(                                \
                            __builtin_amdgcn_ds_bpermute(                       \
                                baddr[j], __float_as_int(_e)));                 \
                } while (0)

                #define CRF_STEP(XF) do {                                       \
                    float _ef[NS];                                              \
                    CRF_BCAST(_ef, XF);                                         \
                    CRF_MAT(_ef);                                               \
                } while (0)

                #define CRF_RENORM() do {                                       \
                    float m = p[0];                                             \
                    _Pragma("unroll")                                           \
                    for (int j = 1; j < NS; ++j) m = fmaxf(m, p[j]);            \
                    float rm = __builtin_amdgcn_rcpf(m);                        \
                    _Pragma("unroll")                                           \
                    for (int j = 0; j < NS; ++j) p[j] *= rm;                    \
                    sc += __logf(m);                                            \
                } while (0)

                int o1 = KDIM * min(1, rem - 1);
                int o2 = KDIM * min(2, rem - 1);
                int o3 = KDIM * min(3, rem - 1);
                float x0 = fp[0], x1 = fp[o1], x2 = fp[o2], x3 = fp[o3];
                fp += 4 * KDIM;

                while (rem >= 8) {
                    float y0 = fp[0], y1 = fp[KDIM], y2 = fp[2 * KDIM], y3 = fp[3 * KDIM];
                    fp += 4 * KDIM;
                    float efA[NS], efB[NS], efC[NS], efD[NS];
                    CRF_BCAST(efA, x0);
                    CRF_BCAST(efB, x1);
                    CRF_BCAST(efC, x2);
                    CRF_BCAST(efD, x3);
                    CRF_MAT(efA); CRF_MAT(efB); CRF_MAT(efC); CRF_MAT(efD);
                    CRF_RENORM();
                    x0 = y0; x1 = y1; x2 = y2; x3 = y3;
                    rem -= 4;
                }
                if (rem > 4) {
                    int e1 = KDIM * min(1, rem - 5);
                    int e2 = KDIM * min(2, rem - 5);
                    float y0 = fp[0], y1 = fp[e1], y2 = fp[e2];
                    float efA[NS], efB[NS], efC[NS], efD[NS];
                    CRF_BCAST(efA, x0);
                    CRF_BCAST(efB, x1);
                    CRF_BCAST(efC, x2);
                    CRF_BCAST(efD, x3);
                    CRF_MAT(efA); CRF_MAT(efB); CRF_MAT(efC); CRF_MAT(efD);
                    CRF_RENORM();
                    x0 = y0; x1 = y1; x2 = y2;
                    rem -= 4;
                }
                CRF_STEP(x0);
                if (rem > 1) CRF_STEP(x1);
                if (rem > 2) CRF_STEP(x2);
                if (rem > 3) CRF_STEP(x3);

                #pragma unroll
                for (int j = 0; j < NS; ++j)
                    Mw[j * 8 + lane8] = __logf(p[j]) + sc;

                #undef CRF_MAT
                #undef CRF_BCAST
                #undef CRF_STEP
                #undef CRF_RENORM
            } else {
                #pragma unroll
                for (int j = 0; j < NS; ++j)
                    Mw[j * 8 + lane8] = (j == lane8) ? 0.f : NEGINF;
            }
        }
    }

    // same-wave LDS write->read: drain DS queue, fence the compiler.
    asm volatile("s_waitcnt lgkmcnt(0)" ::: "memory");

    // ---- in-wave fold: 8 chunk mats -> 1 segment mat; lane l=j*8+i ----
    {
        const int l  = tid & 63;
        const int i  = l & 7;
        float* sg = s_M + widx * 512;

        float A = sg[l];                         // A = M_{c0}
        int baddr[NS];
        #pragma unroll
        for (int k = 0; k < NS; ++k) baddr[k] = ((k << 3) | i) << 2;

        #pragma unroll
        for (int c = 1; c < 8; ++c) {
            const float* Mr = sg + c * 64 + (l & 56);   // row j of Mc
            float4 r0 = *(const float4*)(Mr);
            float4 r1 = *(const float4*)(Mr + 4);
            float ac[NS];
            #pragma unroll
            for (int k = 0; k < NS; ++k)
                ac[k] = __int_as_float(__builtin_amdgcn_ds_bpermute(
                            baddr[k], __float_as_int(A)));
            float t0 = r0.x + ac[0], t1 = r0.y + ac[1], t2 = r0.z + ac[2];
            float t3 = r0.w + ac[3], t4 = r1.x + ac[4], t5 = r1.y + ac[5];
            float t6 = r1.z + ac[6];
            float tm = fmaxf(fmaxf(fmaxf(t0, t1), fmaxf(t2, t3)),
                             fmaxf(fmaxf(t4, t5), t6));
            float sum = ((__expf(t0 - tm) + __expf(t1 - tm)) +
                         (__expf(t2 - tm) + __expf(t3 - tm))) +
                        ((__expf(t4 - tm) + __expf(t5 - tm)) + __expf(t6 - tm));
            A = tm + __logf(sum);
        }
        // segment matrix out (junk rows/cols j==7 / i==7 land in padding)
        g_seg[((size_t)(b * SLICES + s)) * 64 + l] = A;
    }
}

// ---------------------------------------------------------------- kernel B --
__global__ __launch_bounds__(256) void crf_fold_kernel(
    const float* __restrict__ feats,
    const float* __restrict__ trans,
    const int*   __restrict__ tags,
    const int*   __restrict__ lengths,
    const float* __restrict__ g_seg,
    float* __restrict__ out,
    int B, int T)
{
    __shared__ float s_trans[81];
    __shared__ float s_S[512];           // 8 segment mats, stride 64
    __shared__ float s_gold[4];

    const int tid = threadIdx.x;
    const int b   = blockIdx.x;

    if (tid < 81) s_trans[tid] = trans[tid];
    {
        const float* sp = g_seg + (size_t)b * 512;
        s_S[tid]       = sp[tid];
        s_S[tid + 256] = sp[tid + 256];
    }
    __syncthreads();

    const int    len   = lengths[b];
    const int*   tg    = tags  + (size_t)b * T;
    const float* fbase = feats + (size_t)b * T * KDIM;

    // ---- gold score (unrolled-8) ----
    {
        int per = (T >> 8) > 0 ? (T >> 8) : 1;
        int t0  = tid * per;
        float g = 0.f;
        if (t0 < len) {
            int te   = min(t0 + per, len);
            int prev = (t0 == 0) ? START_TAG : tg[t0 - 1];
            if (per == 8) {
                #pragma unroll
                for (int k = 0; k < 8; ++k) {
                    int t   = t0 + k;
                    int tc  = min(t, te - 1);
                    int cur = tg[tc];
                    float v = s_trans[cur * 9 + prev] + fbase[(size_t)tc * KDIM + cur];
                    g += (t < te) ? v : 0.f;
                    prev = cur;
                }
            } else {
                for (int k = 0; k < per; ++k) {
                    int t   = t0 + k;
                    int tc  = min(t, te - 1);
                    int cur = tg[tc];
                    float v = s_trans[cur * 9 + prev] + fbase[(size_t)tc * KDIM + cur];
                    g += (t < te) ? v : 0.f;
                    prev = cur;
                }
            }
            if (len - 1 >= t0 && len - 1 < t0 + per)
                g += s_trans[STOP_TAG * 9 + tg[len - 1]];
        }
        #pragma unroll
        for (int off = 32; off > 0; off >>= 1) g += __shfl_xor(g, off, 64);
        if ((tid & 63) == 0) s_gold[tid >> 6] = g;
    }
    __syncthreads();

    // ---- fold 8 segment matrices with replicated alpha ----
    if (tid < 8) {
        const int  lane  = tid;
        const bool isrow = (lane < NS);
        const int  row   = isrow ? lane : 0;

        float a[NS];
        #pragma unroll
        for (int i = 0; i < NS; ++i)
            a[i] = s_trans[i * 9 + START_TAG] + fbase[i];
        float S;
        {
            float mm = fmaxf(fmaxf(fmaxf(a[0], a[1]), fmaxf(a[2], a[3])),
                             fmaxf(fmaxf(a[4], a[5]), a[6]));
            S = mm;
            #pragma unroll
            for (int i = 0; i < NS; ++i) a[i] -= mm;
        }

        const float* Mr0 = s_S + row * 8;
        float4 mA = *(const float4*)(Mr0);
        float4 mB = *(const float4*)(Mr0 + 4);
        #pragma unroll
        for (int w = 0; w < 8; ++w) {
            int wn = min(w + 1, 7);
            float4 nA = *(const float4*)(Mr0 + wn * 64);
            float4 nB = *(const float4*)(Mr0 + wn * 64 + 4);
            float t0 = mA.x + a[0], t1 = mA.y + a[1], t2 = mA.z + a[2];
            float t3 = mA.w + a[3], t4 = mB.x + a[4], t5 = mB.y + a[5];
            float t6 = mB.z + a[6];
            float tm = fmaxf(fmaxf(fmaxf(t0, t1), fmaxf(t2, t3)),
                             fmaxf(fmaxf(t4, t5), t6));
            float e0 = __expf(t0 - tm), e1 = __expf(t1 - tm), e2 = __expf(t2 - tm);
            float e3 = __expf(t3 - tm), e4 = __expf(t4 - tm), e5 = __expf(t5 - tm);
            float e6 = __expf(t6 - tm);
            float sum = ((e0 + e1) + (e2 + e3)) + ((e4 + e5) + e6);
            float na = isrow ? (tm + __logf(sum)) : NEGINF;
            float b0 = __shfl(na, 0, 8), b1 = __shfl(na, 1, 8), b2 = __shfl(na, 2, 8);
            float b3 = __shfl(na, 3, 8), b4 = __shfl(na, 4, 8), b5 = __shfl(na, 5, 8);
            float b6 = __shfl(na, 6, 8);
            float mm = fmaxf(fmaxf(fmaxf(b0, b1), fmaxf(b2, b3)),
                             fmaxf(fmaxf(b4, b5), b6));
            a[0] = b0 - mm; a[1] = b1 - mm; a[2] = b2 - mm;
            a[3] = b3 - mm; a[4] = b4 - mm; a[5] = b5 - mm;
            a[6] = b6 - mm;
            S += mm;
            mA = nA; mB = nB;
        }

        if (lane == 0) {
            float t0 = a[0] + s_trans[STOP_TAG * 9 + 0];
            float t1 = a[1] + s_trans[STOP_TAG * 9 + 1];
            float t2 = a[2] + s_trans[STOP_TAG * 9 + 2];
            float t3 = a[3] + s_trans[STOP_TAG * 9 + 3];
            float t4 = a[4] + s_trans[STOP_TAG * 9 + 4];
            float t5 = a[5] + s_trans[STOP_TAG * 9 + 5];
            float t6 = a[6] + s_trans[STOP_TAG * 9 + 6];
            float tm = fmaxf(fmaxf(fmaxf(t0, t1), fmaxf(t2, t3)),
                             fmaxf(fmaxf(t4, t5), t6));
            float sum = ((__expf(t0 - tm) + __expf(t1 - tm)) +
                         (__expf(t2 - tm) + __expf(t3 - tm))) +
                        ((__expf(t4 - tm) + __expf(t5 - tm)) + __expf(t6 - tm));
            float fwd = S + tm + __logf(sum);
            float g = s_gold[0] + s_gold[1] + s_gold[2] + s_gold[3];
            atomicAdd(out, (fwd - g) * (1.0f / (float)B));
        }
    }
}

__global__ void init_out_kernel(float* out) {
    if (threadIdx.x == 0) out[0] = 0.f;
}

extern "C" void kernel_launch(void* const* d_in, const int* in_sizes, int n_in,
                              void* d_out, int out_size, void* d_ws, size_t ws_size,
                              hipStream_t stream) {
    const float* feats   = (const float*)d_in[0];
    const float* trans   = (const float*)d_in[1];
    const int*   tags    = (const int*)d_in[2];
    const int*   lengths = (const int*)d_in[3];

    int B = in_sizes[3];
    int T = in_sizes[2] / B;

    float* seg = (float*)d_ws;     // B * SLICES * 64 floats = 2 MB for B=1024

    init_out_kernel<<<1, 64, 0, stream>>>((float*)d_out);
    crf_chunk_kernel<<<B * SLICES / 4, 256, 0, stream>>>(
        feats, trans, lengths, seg, B, T);
    crf_fold_kernel<<<B, 256, 0, stream>>>(
        feats, trans, tags, lengths, seg, (float*)d_out, B, T);
}

// Round 4
// 154.064 us; speedup vs baseline: 1.0703x; 1.0703x over previous
//
#include <hip/hip_runtime.h>

// Fused CRF NLL: B=1024, T=2048, K=9 (START=7, STOP=8).
// TWO-KERNEL structure (load-balanced slices) -- R3 fixed:
//   * launch_bounds(256,4): R3's (256,8) forced VGPR<=64 and spilled ~30MB
//     of scratch onto the serial recurrence (WRITE_SIZE 31.4MB, VGPR=32).
//   * gold score moved INTO kernel A (per-slice partials, ranges aligned to
//     the slice's chunk range for cache reuse) so its dependent tag->feat
//     gather overlaps phase-2 latency instead of running serially after.
//
// Kernel A (crf_chunk_kernel), B*2 blocks x 256 thr:
//   wave = one SLICE s (8 chunks) of sentence b, strided map W = bid*4+widx,
//   s = W/B, b = W%B  -> each CU averages 32 iid slices (balance).
//   Per wave: gold partial for its t-range; 8 chunk 7x7 linear-space transfer
//   matrices (Lb = ceil((len-1)/64), <=32 serial steps; E in SGPRs; lane l
//   loads only f[t][l], shares exp via ds_bpermute; 4-step groups, renorm/4);
//   in-wave 8->1 log-matmul fold (7 steps); segment matrix -> ws.
// Kernel B (crf_fold_kernel), B blocks x 64 thr:
//   stage 8 segment mats, sum 8 gold partials, replicated-alpha fold over 8
//   segments, STOP readout, atomicAdd((fwd-gold)/B).

#define START_TAG 7
#define STOP_TAG  8
#define KDIM      9
#define NS        7
#define CPS       64          // chunks per sentence
#define SLICES    8           // waves (slices) per sentence
#define NEGINF    (-1e30f)

__device__ __forceinline__ float rfl(float x) {
    return __int_as_float(__builtin_amdgcn_readfirstlane(__float_as_int(x)));
}

// ---------------------------------------------------------------- kernel A --
__global__ __launch_bounds__(256, 4) void crf_chunk_kernel(
    const float* __restrict__ feats,
    const float* __restrict__ trans,
    const int*   __restrict__ tags,
    const int*   __restrict__ lengths,
    float* __restrict__ g_seg,
    float* __restrict__ g_gold,
    int B, int T)
{
    __shared__ float s_trans[81];
    __shared__ float s_E[49];
    __shared__ float s_M[4 * 512];       // per-wave 8 chunk mats [k][j*8+i]

    const int tid = threadIdx.x;
    if (tid < 81) s_trans[tid] = trans[tid];
    if (tid >= 128 && tid < 177) {
        int k = tid - 128;
        s_E[k] = __expf(trans[(k / 7) * 9 + (k % 7)]);
    }
    __syncthreads();

    const int widx = tid >> 6;
    const int W    = blockIdx.x * 4 + widx;     // global wave id in [0, 8B)
    const int s    = W / B;                     // slice 0..7
    const int b    = W - s * B;                 // sentence

    const int    len   = lengths[b];
    const int*   tg    = tags  + (size_t)b * T;
    const float* fbase = feats + (size_t)b * T * KDIM;
    const int    Lb    = (len > 1) ? ((len - 1 + CPS - 1) / CPS) : 1;

    // ---- gold partial for this slice's t-range ----
    {
        const int gs = (s == 0) ? 0 : 1 + s * 8 * Lb;
        const int ge = (s == SLICES - 1) ? len : min(1 + (s + 1) * 8 * Lb, len);
        float g = 0.f;
        if (gs < ge) {
            int span = ge - gs;
            int per  = (span + 63) >> 6;
            int t0   = gs + (tid & 63) * per;
            if (t0 < ge) {
                int te   = min(t0 + per, ge);
                int prev = (t0 == 0) ? START_TAG : tg[t0 - 1];
                for (int k = 0; k < per; ++k) {
                    int t   = t0 + k;
                    int tc  = min(t, te - 1);
                    int cur = tg[tc];
                    float v = s_trans[cur * 9 + prev] + fbase[(size_t)tc * KDIM + cur];
                    g += (t < te) ? v : 0.f;
                    prev = cur;
                }
                if (len - 1 >= t0 && len - 1 < t0 + per && len - 1 < ge)
                    g += s_trans[STOP_TAG * 9 + tg[len - 1]];
            }
        }
        #pragma unroll
        for (int off = 32; off > 0; off >>= 1) g += __shfl_xor(g, off, 64);
        if ((tid & 63) == 0) g_gold[b * SLICES + s] = g;
    }

    // ---- phase 2: 8 chunk matrices for this slice ----
    {
        const int lane8  = tid & 7;
        const int k      = (tid >> 3) & 7;      // chunk-in-slice
        const int c      = s * 8 + k;           // global chunk of sentence
        const int tstart = 1 + c * Lb;
        const int tend   = min(tstart + Lb, len);

        if (lane8 < NS) {
            float* Mw = s_M + widx * 512 + k * 64;
            if (tstart < tend) {
                float E[49];
                #pragma unroll
                for (int e = 0; e < 49; ++e) E[e] = rfl(s_E[e]);

                int baddr[NS];
                #pragma unroll
                for (int j = 0; j < NS; ++j) baddr[j] = (((tid & 56) | j) << 2);

                float p[NS];
                #pragma unroll
                for (int j = 0; j < NS; ++j) p[j] = (j == lane8) ? 1.f : 0.f;
                float sc = 0.f;
                int rem = tend - tstart;

                const float* fp = fbase + (size_t)tstart * KDIM + lane8;

                #define CRF_MAT(EF) do {                                        \
                    float q[NS];                                                \
                    _Pragma("unroll")                                           \
                    for (int j = 0; j < NS; ++j) {                              \
                        float acc = E[j * 7] * p[0];                            \
                        _Pragma("unroll")                                       \
                        for (int i = 1; i < NS; ++i)                            \
                            acc = fmaf(E[j * 7 + i], p[i], acc);                \
                        q[j] = acc;                                             \
                    }                                                           \
                    _Pragma("unroll")                                           \
                    for (int j = 0; j < NS; ++j) p[j] = q[j] * EF[j];           \
                } while (0)

                #define CRF_BCAST(DST, XF) do {                                 \
                    float _e = __expf(XF);                                      \
                    _Pragma("unroll")                                           \
                    for (int j = 0; j < NS; ++j)                                \
                        DST[j] = __int_as_float(                                \
                            __builtin_amdgcn_ds_bpermute(                       \
                                baddr[j], __float_as_int(_e)));                 \
                } while (0)

                #define CRF_STEP(XF) do {                                       \
                    float _ef[NS];                                              \
                    CRF_BCAST(_ef, XF);                                         \
                    CRF_MAT(_ef);                                               \
                } while (0)

                #define CRF_RENORM() do {                                       \
                    float m = p[0];                                             \
                    _Pragma("unroll")                                           \
                    for (int j = 1; j < NS; ++j) m = fmaxf(m, p[j]);            \
                    float rm = __builtin_amdgcn_rcpf(m);                        \
                    _Pragma("unroll")                                           \
                    for (int j = 0; j < NS; ++j) p[j] *= rm;                    \
                    sc += __logf(m);                                            \
                } while (0)

                int o1 = KDIM * min(1, rem - 1);
                int o2 = KDIM * min(2, rem - 1);
                int o3 = KDIM * min(3, rem - 1);
                float x0 = fp[0], x1 = fp[o1], x2 = fp[o2], x3 = fp[o3];
                fp += 4 * KDIM;

                while (rem >= 8) {
                    float y0 = fp[0], y1 = fp[KDIM], y2 = fp[2 * KDIM], y3 = fp[3 * KDIM];
                    fp += 4 * KDIM;
                    float efA[NS], efB[NS], efC[NS], efD[NS];
                    CRF_BCAST(efA, x0);
                    CRF_BCAST(efB, x1);
                    CRF_BCAST(efC, x2);
                    CRF_BCAST(efD, x3);
                    CRF_MAT(efA); CRF_MAT(efB); CRF_MAT(efC); CRF_MAT(efD);
                    CRF_RENORM();
                    x0 = y0; x1 = y1; x2 = y2; x3 = y3;
                    rem -= 4;
                }
                if (rem > 4) {
                    int e1 = KDIM * min(1, rem - 5);
                    int e2 = KDIM * min(2, rem - 5);
                    float y0 = fp[0], y1 = fp[e1], y2 = fp[e2];
                    float efA[NS], efB[NS], efC[NS], efD[NS];
                    CRF_BCAST(efA, x0);
                    CRF_BCAST(efB, x1);
                    CRF_BCAST(efC, x2);
                    CRF_BCAST(efD, x3);
                    CRF_MAT(efA); CRF_MAT(efB); CRF_MAT(efC); CRF_MAT(efD);
                    CRF_RENORM();
                    x0 = y0; x1 = y1; x2 = y2;
                    rem -= 4;
                }
                CRF_STEP(x0);
                if (rem > 1) CRF_STEP(x1);
                if (rem > 2) CRF_STEP(x2);
                if (rem > 3) CRF_STEP(x3);

                #pragma unroll
                for (int j = 0; j < NS; ++j)
                    Mw[j * 8 + lane8] = __logf(p[j]) + sc;

                #undef CRF_MAT
                #undef CRF_BCAST
                #undef CRF_STEP
                #undef CRF_RENORM
            } else {
                #pragma unroll
                for (int j = 0; j < NS; ++j)
                    Mw[j * 8 + lane8] = (j == lane8) ? 0.f : NEGINF;
            }
        }
    }

    // same-wave LDS write->read: drain DS queue, fence the compiler.
    asm volatile("s_waitcnt lgkmcnt(0)" ::: "memory");

    // ---- in-wave fold: 8 chunk mats -> 1 segment mat; lane l=j*8+i ----
    {
        const int l  = tid & 63;
        const int i  = l & 7;
        float* sg = s_M + widx * 512;

        float A = sg[l];                         // A = M_{c0}
        int baddr[NS];
        #pragma unroll
        for (int k = 0; k < NS; ++k) baddr[k] = ((k << 3) | i) << 2;

        #pragma unroll
        for (int c = 1; c < 8; ++c) {
            const float* Mr = sg + c * 64 + (l & 56);   // row j of Mc
            float4 r0 = *(const float4*)(Mr);
            float4 r1 = *(const float4*)(Mr + 4);
            float ac[NS];
            #pragma unroll
            for (int k = 0; k < NS; ++k)
                ac[k] = __int_as_float(__builtin_amdgcn_ds_bpermute(
                            baddr[k], __float_as_int(A)));
            float t0 = r0.x + ac[0], t1 = r0.y + ac[1], t2 = r0.z + ac[2];
            float t3 = r0.w + ac[3], t4 = r1.x + ac[4], t5 = r1.y + ac[5];
            float t6 = r1.z + ac[6];
            float tm = fmaxf(fmaxf(fmaxf(t0, t1), fmaxf(t2, t3)),
                             fmaxf(fmaxf(t4, t5), t6));
            float sum = ((__expf(t0 - tm) + __expf(t1 - tm)) +
                         (__expf(t2 - tm) + __expf(t3 - tm))) +
                        ((__expf(t4 - tm) + __expf(t5 - tm)) + __expf(t6 - tm));
            A = tm + __logf(sum);
        }
        // segment matrix out (junk rows/cols j==7 / i==7 land in padding)
        g_seg[((size_t)(b * SLICES + s)) * 64 + l] = A;
    }
}

// ---------------------------------------------------------------- kernel B --
__global__ __launch_bounds__(64) void crf_fold_kernel(
    const float* __restrict__ feats,
    const float* __restrict__ trans,
    const float* __restrict__ g_seg,
    const float* __restrict__ g_gold,
    float* __restrict__ out,
    int B, int T)
{
    __shared__ float s_S[512];           // 8 segment mats, stride 64

    const int tid = threadIdx.x;
    const int b   = blockIdx.x;

    {
        const float* sp = g_seg + (size_t)b * 512;
        #pragma unroll
        for (int k = 0; k < 8; ++k) s_S[tid + 64 * k] = sp[tid + 64 * k];
    }
    // sum the 8 gold partials (lanes 0..7)
    float gg = (tid < 8) ? g_gold[b * SLICES + tid] : 0.f;
    gg += __shfl_xor(gg, 1, 8);
    gg += __shfl_xor(gg, 2, 8);
    gg += __shfl_xor(gg, 4, 8);
    __syncthreads();

    if (tid < 8) {
        const int  lane  = tid;
        const bool isrow = (lane < NS);
        const int  row   = isrow ? lane : 0;
        const float* fbase = feats + (size_t)b * T * KDIM;

        float a[NS];
        #pragma unroll
        for (int i = 0; i < NS; ++i)
            a[i] = trans[i * 9 + START_TAG] + fbase[i];
        float S;
        {
            float mm = fmaxf(fmaxf(fmaxf(a[0], a[1]), fmaxf(a[2], a[3])),
                             fmaxf(fmaxf(a[4], a[5]), a[6]));
            S = mm;
            #pragma unroll
            for (int i = 0; i < NS; ++i) a[i] -= mm;
        }

        const float* Mr0 = s_S + row * 8;
        float4 mA = *(const float4*)(Mr0);
        float4 mB = *(const float4*)(Mr0 + 4);
        #pragma unroll
        for (int w = 0; w < 8; ++w) {
            int wn = min(w + 1, 7);
            float4 nA = *(const float4*)(Mr0 + wn * 64);
            float4 nB = *(const float4*)(Mr0 + wn * 64 + 4);
            float t0 = mA.x + a[0], t1 = mA.y + a[1], t2 = mA.z + a[2];
            float t3 = mA.w + a[3], t4 = mB.x + a[4], t5 = mB.y + a[5];
            float t6 = mB.z + a[6];
            float tm = fmaxf(fmaxf(fmaxf(t0, t1), fmaxf(t2, t3)),
                             fmaxf(fmaxf(t4, t5), t6));
            float e0 = __expf(t0 - tm), e1 = __expf(t1 - tm), e2 = __expf(t2 - tm);
            float e3 = __expf(t3 - tm), e4 = __expf(t4 - tm), e5 = __expf(t5 - tm);
            float e6 = __expf(t6 - tm);
            float sum = ((e0 + e1) + (e2 + e3)) + ((e4 + e5) + e6);
            float na = isrow ? (tm + __logf(sum)) : NEGINF;
            float b0 = __shfl(na, 0, 8), b1 = __shfl(na, 1, 8), b2 = __shfl(na, 2, 8);
            float b3 = __shfl(na, 3, 8), b4 = __shfl(na, 4, 8), b5 = __shfl(na, 5, 8);
            float b6 = __shfl(na, 6, 8);
            float mm = fmaxf(fmaxf(fmaxf(b0, b1), fmaxf(b2, b3)),
                             fmaxf(fmaxf(b4, b5), b6));
            a[0] = b0 - mm; a[1] = b1 - mm; a[2] = b2 - mm;
            a[3] = b3 - mm; a[4] = b4 - mm; a[5] = b5 - mm;
            a[6] = b6 - mm;
            S += mm;
            mA = nA; mB = nB;
        }

        if (lane == 0) {
            float t0 = a[0] + trans[STOP_TAG * 9 + 0];
            float t1 = a[1] + trans[STOP_TAG * 9 + 1];
            float t2 = a[2] + trans[STOP_TAG * 9 + 2];
            float t3 = a[3] + trans[STOP_TAG * 9 + 3];
            float t4 = a[4] + trans[STOP_TAG * 9 + 4];
            float t5 = a[5] + trans[STOP_TAG * 9 + 5];
            float t6 = a[6] + trans[STOP_TAG * 9 + 6];
            float tm = fmaxf(fmaxf(fmaxf(t0, t1), fmaxf(t2, t3)),
                             fmaxf(fmaxf(t4, t5), t6));
            float sum = ((__expf(t0 - tm) + __expf(t1 - tm)) +
                         (__expf(t2 - tm) + __expf(t3 - tm))) +
                        ((__expf(t4 - tm) + __expf(t5 - tm)) + __expf(t6 - tm));
            float fwd = S + tm + __logf(sum);
            atomicAdd(out, (fwd - gg) * (1.0f / (float)B));
        }
    }
}

__global__ void init_out_kernel(float* out) {
    if (threadIdx.x == 0) out[0] = 0.f;
}

extern "C" void kernel_launch(void* const* d_in, const int* in_sizes, int n_in,
                              void* d_out, int out_size, void* d_ws, size_t ws_size,
                              hipStream_t stream) {
    const float* feats   = (const float*)d_in[0];
    const float* trans   = (const float*)d_in[1];
    const int*   tags    = (const int*)d_in[2];
    const int*   lengths = (const int*)d_in[3];

    int B = in_sizes[3];
    int T = in_sizes[2] / B;

    float* seg  = (float*)d_ws;                         // B*8*64 floats = 2 MB
    float* gold = seg + (size_t)B * SLICES * 64;        // B*8 floats = 32 KB

    init_out_kernel<<<1, 64, 0, stream>>>((float*)d_out);
    crf_chunk_kernel<<<B * SLICES / 4, 256, 0, stream>>>(
        feats, trans, tags, lengths, seg, gold, B, T);
    crf_fold_kernel<<<B, 64, 0, stream>>>(
        feats, trans, seg, gold, (float*)d_out, B, T);
}